// Round 1
// baseline (185.765 us; speedup 1.0000x reference)
//
#include <hip/hip_runtime.h>
#include <stdint.h>

// Problem constants (fixed by the reference).
#define BB 32
#define HH 512
#define WW 512
#define HWSZ (HH * WW)        // 262144 elements per batch
#define PP 8192               // samples per batch
#define WPB (HWSZ / 64)       // 4096 bitmap words per batch
#define EPSV 1e-5f

// ---------------------------------------------------------------------------
// K1: build per-wave 64-bit mask bitmap. gid = element index over B*HW.
// Each wave's __ballot produces one word; bit l <-> element (word_base + l).
// ---------------------------------------------------------------------------
__global__ __launch_bounds__(256) void k_bitmap(const int* __restrict__ mask,
                                                uint64_t* __restrict__ words) {
    int gid = blockIdx.x * 256 + threadIdx.x;
    int m = mask[gid];
    unsigned long long ball = __ballot(m != 0);
    if ((threadIdx.x & 63) == 0) {
        words[gid >> 6] = (uint64_t)ball;
    }
}

// ---------------------------------------------------------------------------
// K2: per-batch exclusive prefix of word popcounts + total valid count.
// One block (256 threads) per batch; each thread owns 16 consecutive words.
// ---------------------------------------------------------------------------
__global__ __launch_bounds__(256) void k_scan(const uint64_t* __restrict__ words,
                                              uint32_t* __restrict__ wprefix,
                                              uint32_t* __restrict__ valid_num) {
    __shared__ uint32_t tot[256];
    int b = blockIdx.x;
    int t = threadIdx.x;
    const uint64_t* wb = words + (size_t)b * WPB;
    uint32_t pc[16];
    uint32_t s = 0;
    int base = t * 16;
#pragma unroll
    for (int i = 0; i < 16; ++i) {
        pc[i] = (uint32_t)__popcll(wb[base + i]);
        s += pc[i];
    }
    tot[t] = s;
    __syncthreads();
    if (t == 0) {
        uint32_t run = 0;
        for (int i = 0; i < 256; ++i) {
            uint32_t v = tot[i];
            tot[i] = run;
            run += v;
        }
        valid_num[b] = run;
    }
    __syncthreads();
    uint32_t off = tot[t];
    uint32_t* wp = wprefix + (size_t)b * WPB;
#pragma unroll
    for (int i = 0; i < 16; ++i) {
        wp[base + i] = off;
        off += pc[i];
    }
}

// ---------------------------------------------------------------------------
// K3: sampling + loss accumulation. One block = 256 samples, all in one batch
// (8192 samples/batch = 32 blocks/batch). wprefix for the batch staged in LDS
// (16 KB) for the binary search; bit-select is branch-free popcount halving.
// ---------------------------------------------------------------------------
__global__ __launch_bounds__(256) void k_loss(const float* __restrict__ d3,
                                              const float* __restrict__ dp,
                                              const int* __restrict__ s1raw,
                                              const int* __restrict__ s2raw,
                                              const uint64_t* __restrict__ words,
                                              const uint32_t* __restrict__ wprefix,
                                              const uint32_t* __restrict__ valid_num,
                                              float* __restrict__ accf,
                                              uint32_t* __restrict__ accu) {
    __shared__ uint32_t wp[WPB];
    __shared__ float sv1[4], sv2[4];
    __shared__ uint32_t sc1[4], sc2[4];

    int b = blockIdx.x >> 5;  // 32 blocks per batch
    int gid = blockIdx.x * 256 + threadIdx.x;

    const uint32_t* wpg = wprefix + (size_t)b * WPB;
    for (int i = threadIdx.x; i < WPB; i += 256) wp[i] = wpg[i];
    __syncthreads();

    uint32_t vn = valid_num[b];
    const uint64_t* wb = words + (size_t)b * WPB;
    const float* d3b = d3 + (size_t)b * HWSZ;
    const float* dpb = dp + (size_t)b * HWSZ;

    uint32_t k1 = (uint32_t)(s1raw[gid] % (int)vn);
    uint32_t k2 = (uint32_t)(s2raw[gid] % (int)vn);

    auto sel = [&](uint32_t k) -> int {
        // binary search: largest w with wp[w] <= k  (wp[0] == 0 <= k always)
        int lo = 0, hi = WPB;
        while (hi - lo > 1) {
            int mid = (lo + hi) >> 1;
            if (wp[mid] <= k) lo = mid; else hi = mid;
        }
        uint32_t r = k - wp[lo];
        uint64_t x = wb[lo];
        int pos = lo << 6;
        uint32_t c = (uint32_t)__popcll(x & 0xFFFFFFFFull);
        if (r >= c) { r -= c; pos += 32; x >>= 32; }
        uint32_t y = (uint32_t)x;
        c = (uint32_t)__popc(y & 0xFFFFu); if (r >= c) { r -= c; pos += 16; y >>= 16; }
        c = (uint32_t)__popc(y & 0xFFu);   if (r >= c) { r -= c; pos += 8;  y >>= 8; }
        c = (uint32_t)__popc(y & 0xFu);    if (r >= c) { r -= c; pos += 4;  y >>= 4; }
        c = (uint32_t)__popc(y & 0x3u);    if (r >= c) { r -= c; pos += 2;  y >>= 2; }
        c = y & 1u;                        if (r >= c) { pos += 1; }
        return pos;
    };

    int i1 = sel(k1);
    int i2 = sel(k2);

    float a  = d3b[i1];
    float bv = d3b[i2];
    float p1 = dpb[i1];
    float p2 = dpb[i2];
    float diff = p1 - p2;

    bool gt = a > bv + EPSV;
    bool lt = a < bv - EPSV;
    float v1 = gt ? fmaxf(-diff, 0.0f) : 0.0f;
    float v2 = lt ? fmaxf(diff, 0.0f) : 0.0f;
    uint32_t c1 = gt ? 1u : 0u;
    uint32_t c2 = lt ? 1u : 0u;

    // wave (64-lane) reduction
#pragma unroll
    for (int off = 32; off > 0; off >>= 1) {
        v1 += __shfl_down(v1, off);
        v2 += __shfl_down(v2, off);
        c1 += __shfl_down(c1, off);
        c2 += __shfl_down(c2, off);
    }
    int wid = threadIdx.x >> 6;
    if ((threadIdx.x & 63) == 0) {
        sv1[wid] = v1; sv2[wid] = v2; sc1[wid] = c1; sc2[wid] = c2;
    }
    __syncthreads();
    if (threadIdx.x == 0) {
        float t1 = 0.f, t2 = 0.f;
        uint32_t u1 = 0, u2 = 0;
        for (int i = 0; i < 4; ++i) { t1 += sv1[i]; t2 += sv2[i]; u1 += sc1[i]; u2 += sc2[i]; }
        atomicAdd(&accf[0], t1);
        atomicAdd(&accf[1], t2);
        atomicAdd(&accu[0], u1);
        atomicAdd(&accu[1], u2);
    }
}

// ---------------------------------------------------------------------------
// K4: combine into the scalar loss.
// ---------------------------------------------------------------------------
__global__ void k_final(const float* __restrict__ accf,
                        const uint32_t* __restrict__ accu,
                        float* __restrict__ out) {
    float l1 = accf[0] / (float)accu[0];
    float l2 = accf[1] / (float)accu[1];
    out[0] = 0.5f * (l1 + l2);
}

extern "C" void kernel_launch(void* const* d_in, const int* in_sizes, int n_in,
                              void* d_out, int out_size, void* d_ws, size_t ws_size,
                              hipStream_t stream) {
    const float* d3  = (const float*)d_in[0];  // depth_3dmm [B,1,H,W]
    const float* dp  = (const float*)d_in[1];  // depth_pigan [B,1,H,W]
    const int*  mask = (const int*)d_in[2];    // mask [B,1,H,W]
    const int*  s1   = (const int*)d_in[3];    // sample1_raw [B,P]
    const int*  s2   = (const int*)d_in[4];    // sample2_raw [B,P]
    float* out = (float*)d_out;

    char* ws = (char*)d_ws;
    uint64_t* words     = (uint64_t*)(ws);                 // 32*4096*8 = 1,048,576 B
    uint32_t* wprefix   = (uint32_t*)(ws + 1048576);       //   524,288 B
    uint32_t* valid_num = (uint32_t*)(ws + 1572864);       //       128 B
    float*    accf      = (float*)(ws + 1572992);          // 2 floats
    uint32_t* accu      = (uint32_t*)(ws + 1573000);       // 2 uints

    hipMemsetAsync(accf, 0, 16, stream);  // zero accumulators (ws is 0xAA-poisoned)

    k_bitmap<<<(BB * HWSZ) / 256, 256, 0, stream>>>(mask, words);
    k_scan<<<BB, 256, 0, stream>>>(words, wprefix, valid_num);
    k_loss<<<(BB * PP) / 256, 256, 0, stream>>>(d3, dp, s1, s2, words, wprefix,
                                                valid_num, accf, accu);
    k_final<<<1, 1, 0, stream>>>(accf, accu, out);
}